// Round 4
// baseline (340.425 us; speedup 1.0000x reference)
//
#include <hip/hip_runtime.h>
#include <hip/hip_bf16.h>

// BiAttention, round 4 = round 3 + V-DMA omap chunk-crossing fix.
// Flash core: S^T = K.Q^T and O^T = V^T.P^T with fragment-major LDS layouts
// (every ds_read is base + lane*16, conflict-free), staged via
// global_load_lds DMA double-buffer (1 barrier/iter). bf16 copies of memory
// (row-major + m-chunk-transposed) are materialized by dots_kernel into the
// byte-space of out segment 0 (only overwritten later by assembly_kernel).
// weight_two path: logits = idot + rowmax are O(8), so exp without max
// subtraction -> single atomic pass (o2_kernel), normalized in assembly.

typedef __bf16 bf16_t;
typedef bf16_t bf16x4 __attribute__((ext_vector_type(4)));
typedef bf16_t bf16x8 __attribute__((ext_vector_type(8)));
typedef float  f32x16 __attribute__((ext_vector_type(16)));

#define NB 8
#define NL 2048
#define NM 2048
#define ND 256
#define OUTW 1024
#define MT 32
#define MH 1024
#define NIT 32              // MH/MT
#define LT 128
#define MEMT_X0 8388608u    // byte offset of transposed bf16 copy in seg0 space
#define FLASH_LDS 73728     // 2*32KB kv dbuf + 8KB pfrag

// seg0 byte-space map: flat byte x -> out byte offset. 1KB chunks of x map to
// 4KB-strided rows of out. Any offset added AFTER omap must not cross a 1KB
// chunk in x-space; chunk steps must be added as multiples of 4096.
__device__ __forceinline__ unsigned omap(unsigned x) {
    return ((x >> 10) << 12) | (x & 1023u);
}

__device__ __forceinline__ void dma16(const void* g, void* l) {
    __builtin_amdgcn_global_load_lds(
        (const __attribute__((address_space(1))) unsigned int*)g,
        (__attribute__((address_space(3))) unsigned int*)l, 16, 0, 0);
}

// ---- Kernel A: idot, mbias, and bf16 copies of memory into out-seg0 --------
__global__ __launch_bounds__(256) void dots_kernel(
    const float* __restrict__ input, const float* __restrict__ memory,
    const float* __restrict__ mask, const float* __restrict__ w_input,
    const float* __restrict__ w_memory,
    float* __restrict__ ws_idot, float* __restrict__ ws_mbias,
    char* __restrict__ outc)
{
    int gid  = blockIdx.x * 4 + (threadIdx.x >> 6);   // 0..32767
    int lane = threadIdx.x & 63;
    bool is_mem = gid >= NB * NL;
    int row = is_mem ? gid - NB * NL : gid;
    const float* src = (is_mem ? memory : input) + (size_t)row * ND + lane * 4;
    const float* w   = (is_mem ? w_memory : w_input) + lane * 4;
    float4 v = *(const float4*)src;
    float4 wv = *(const float4*)w;
    float s = v.x * wv.x + v.y * wv.y + v.z * wv.z + v.w * wv.w;
    #pragma unroll
    for (int off = 1; off < 64; off <<= 1) s += __shfl_xor(s, off, 64);

    if (is_mem) {
        // bf16 row-major copy
        bf16x4 bv;
        bv[0] = (bf16_t)v.x; bv[1] = (bf16_t)v.y;
        bv[2] = (bf16_t)v.z; bv[3] = (bf16_t)v.w;
        unsigned x = 2u * ((unsigned)row * ND + lane * 4);
        *(bf16x4*)(outc + omap(x)) = bv;
        // bf16 m-chunked transposed copy: layout [b][m>>3][d][m&7]
        int b = row >> 11, m = row & 2047;
        unsigned base = ((unsigned)(b * 256 + (m >> 3)) * ND);
        #pragma unroll
        for (int j = 0; j < 4; ++j) {
            int d = lane * 4 + j;
            unsigned xT = MEMT_X0 + 2u * ((base + d) * 8 + (m & 7));
            float val = ((const float*)&v)[j];
            *(bf16_t*)(outc + omap(xT)) = (bf16_t)val;
        }
        if (lane == 0) ws_mbias[row] = s - 1e30f * (1.0f - mask[row]);
    } else {
        if (lane == 0) ws_idot[row] = s;
    }
}

// ---- Kernel B: flash attention partials ------------------------------------
// grid 256 = lt*16 + b*2 + half; 4 waves; wave w owns L rows [w*32, w*32+32).
__global__ __launch_bounds__(256, 1) void flash_kernel(
    const float* __restrict__ input, const float* __restrict__ dot_scale,
    const float* __restrict__ ws_mbias, const char* __restrict__ outc,
    float* __restrict__ out, float* __restrict__ ws_l, float* __restrict__ ws_m)
{
    extern __shared__ __align__(16) char smem[];
    // [0,32768): buf0 = kbuf(16K)+vbuf(16K); [32768,65536): buf1; [65536,73728): pfrag

    int bid = blockIdx.x;
    int half = bid & 1, b = (bid >> 1) & 7, lt = bid >> 4;
    int l0 = lt * LT;
    int m_base = half * MH;
    int t = threadIdx.x, w = t >> 6, lane = t & 63;
    int c = lane & 31, h = lane >> 5;

    // Q fragments in registers (B-operand; col = lane&31 = l, k contiguous d)
    const float* qrow = input + (size_t)(b * NL + l0 + w * 32 + c) * ND;
    bf16x8 qf[16];
    #pragma unroll
    for (int ks = 0; ks < 16; ++ks) {
        int d0 = ks * 16 + h * 8;
        float4 a0 = *(const float4*)(qrow + d0);
        float4 a1 = *(const float4*)(qrow + d0 + 4);
        float4 s0 = *(const float4*)(dot_scale + d0);
        float4 s1 = *(const float4*)(dot_scale + d0 + 4);
        qf[ks][0] = (bf16_t)(a0.x * s0.x); qf[ks][1] = (bf16_t)(a0.y * s0.y);
        qf[ks][2] = (bf16_t)(a0.z * s0.z); qf[ks][3] = (bf16_t)(a0.w * s0.w);
        qf[ks][4] = (bf16_t)(a1.x * s1.x); qf[ks][5] = (bf16_t)(a1.y * s1.y);
        qf[ks][6] = (bf16_t)(a1.z * s1.z); qf[ks][7] = (bf16_t)(a1.w * s1.w);
    }

    // Per-lane DMA source bases (mapped through omap once; later increments
    // stay within-chunk or step whole chunks by multiples of 4096).
    unsigned xk = 2u * (((unsigned)(b * NM + m_base + c)) * ND + h * 8);
    const char* kg = outc + omap(xk);
    unsigned xv = MEMT_X0 +
        2u * ((((unsigned)(b * 256 + (m_base >> 3) + h)) * ND + c) * 8);
    const char* vg = outc + omap(xv);

    char* buf0 = smem;
    char* buf1 = smem + 32768;

    // prologue: stage tile 0 into buf0
    #pragma unroll
    for (int j = 0; j < 4; ++j) {
        int i = 4 * w + j;
        int ks = i >> 3, dt = i & 7;
        dma16(kg + i * 32, buf0 + i * 1024);
        // V x-space offset: ks*2 m-chunks + dt*32 d-slots
        //   out-space: ks*32768 + (dt>>1)*4096 + (dt&1)*512  (chunk-safe)
        dma16(vg + ks * 32768 + (dt >> 1) * 4096 + (dt & 1) * 512,
              buf0 + 16384 + i * 1024);
    }
    kg += 65536; vg += 65536;

    f32x16 oaccT[8];
    #pragma unroll
    for (int i = 0; i < 8; ++i)
        #pragma unroll
        for (int r = 0; r < 16; ++r) oaccT[i][r] = 0.f;
    float lsum = 0.f, mmax = -3e38f;

    const float* mb_base = ws_mbias + b * NM;
    bf16_t* pfw = (bf16_t*)(smem + 65536 + w * 2048);

    #pragma unroll 1
    for (int it = 0; it < NIT; ++it) {
        int m0 = m_base + it * MT;
        asm volatile("s_waitcnt vmcnt(0)" ::: "memory"); // my DMA for cur done
        __syncthreads();                                  // all waves' DMA visible
        const char* cb = (it & 1) ? buf1 : buf0;
        char* nb = (it & 1) ? buf0 : buf1;
        const bf16_t* kb = (const bf16_t*)cb;
        const bf16_t* vb = (const bf16_t*)(cb + 16384);
        if (it + 1 < NIT) {   // stage next tile (safe: barrier above)
            #pragma unroll
            for (int j = 0; j < 4; ++j) {
                int i = 4 * w + j;
                int ks = i >> 3, dt = i & 7;
                dma16(kg + i * 32, nb + i * 1024);
                dma16(vg + ks * 32768 + (dt >> 1) * 4096 + (dt & 1) * 512,
                      nb + 16384 + i * 1024);
            }
            kg += 65536; vg += 65536;
        }
        float mb[16];
        #pragma unroll
        for (int r = 0; r < 16; ++r)
            mb[r] = mb_base[m0 + ((r & 3) + 8 * (r >> 2) + 4 * h)];
        // QK: S^T = K . Q^T (two interleaved accumulator chains)
        f32x16 Sa, Sb;
        #pragma unroll
        for (int r = 0; r < 16; ++r) { Sa[r] = 0.f; Sb[r] = 0.f; }
        #pragma unroll
        for (int ks = 0; ks < 16; ks += 2) {
            bf16x8 k0 = *(const bf16x8*)(kb + ks * 512 + lane * 8);
            bf16x8 k1 = *(const bf16x8*)(kb + (ks + 1) * 512 + lane * 8);
            Sa = __builtin_amdgcn_mfma_f32_32x32x16_bf16(k0, qf[ks], Sa, 0, 0, 0);
            Sb = __builtin_amdgcn_mfma_f32_32x32x16_bf16(k1, qf[ks + 1], Sb, 0, 0, 0);
        }
        // P^T = exp(S^T + mdot): pack 4 consecutive m per lane -> b64 writes
        #pragma unroll
        for (int j2 = 0; j2 < 4; ++j2) {
            bf16x4 pk;
            #pragma unroll
            for (int q = 0; q < 4; ++q) {
                int r = j2 * 4 + q;
                float v = Sa[r] + Sb[r] + mb[r];
                mmax = fmaxf(mmax, v);
                float e = __expf(v);
                lsum += e;
                pk[q] = (bf16_t)e;
            }
            *(bf16x4*)(pfw + j2 * 256 + c * 8 + h * 4) = pk;
        }
        asm volatile("s_waitcnt lgkmcnt(0)" ::: "memory");
        // PV: O^T += V^T . P^T (8 independent d-tiles per ks)
        #pragma unroll
        for (int ks = 0; ks < 2; ++ks) {
            bf16x8 pb = *(const bf16x8*)(pfw + ks * 512 + lane * 8);
            #pragma unroll
            for (int dt = 0; dt < 8; ++dt) {
                bf16x8 vv = *(const bf16x8*)(vb + (ks * 8 + dt) * 512 + lane * 8);
                oaccT[dt] = __builtin_amdgcn_mfma_f32_32x32x16_bf16(vv, pb, oaccT[dt], 0, 0, 0);
            }
        }
    }

    // l-sum / row-max finalize (per-lane over m, + h-half merge)
    mmax = fmaxf(mmax, __shfl_xor(mmax, 32, 64));
    lsum += __shfl_xor(lsum, 32, 64);
    if (lane < 32) {
        int row = b * NL + l0 + w * 32 + lane;
        ws_l[half * (NB * NL) + row] = lsum;
        ws_m[half * (NB * NL) + row] = mmax;
    }
    // epilogue: O^T -> coalesced O via per-wave LDS patch (in free buf0 space;
    // last iter reads buf1, so buf0 is dead here for every wave)
    float* patch = (float*)(smem + w * 4352);   // [32 d][stride 33] floats
    float* oseg = out + (size_t)(b * NL + l0 + w * 32) * OUTW + ND * (1 + half);
    #pragma unroll 1
    for (int dt = 0; dt < 8; ++dt) {
        asm volatile("s_waitcnt lgkmcnt(0)" ::: "memory");
        #pragma unroll
        for (int r = 0; r < 16; ++r)
            patch[((r & 3) + 8 * (r >> 2) + 4 * h) * 33 + c] = oaccT[dt][r];
        asm volatile("s_waitcnt lgkmcnt(0)" ::: "memory");
        #pragma unroll
        for (int rr = 0; rr < 16; ++rr) {
            float val = patch[c * 33 + rr * 2 + h];
            oseg[(size_t)(rr * 2 + h) * OUTW + dt * 32 + c] = val;
        }
    }
}

// ---- Kernel C: output_two numerator/denominator (no separate softmax) ------
__global__ __launch_bounds__(256) void o2_kernel(
    const float* __restrict__ input, const float* __restrict__ ws_idot,
    const float* __restrict__ ws_m, float* __restrict__ ws_num,
    float* __restrict__ ws_den)
{
    int b = blockIdx.x >> 4, slice = blockIdx.x & 15;
    int t = threadIdx.x;
    int lgrp = t >> 6, d4 = (t & 63) * 4;
    float4 acc = {0.f, 0.f, 0.f, 0.f};
    float esum = 0.f;
    for (int i = 0; i < 32; ++i) {
        int row = b * NL + slice * 128 + lgrp * 32 + i;
        float e = __expf(ws_idot[row] + fmaxf(ws_m[row], ws_m[NB * NL + row]));
        float4 v = *(const float4*)(input + (size_t)row * ND + d4);
        acc.x += e * v.x; acc.y += e * v.y;
        acc.z += e * v.z; acc.w += e * v.w;
        esum += e;
    }
    float* dst = ws_num + b * ND + d4;
    atomicAdd(dst + 0, acc.x); atomicAdd(dst + 1, acc.y);
    atomicAdd(dst + 2, acc.z); atomicAdd(dst + 3, acc.w);
    if ((t & 63) == 0) atomicAdd(ws_den + b, esum);
}

// ---- Kernel D: combine halves + assemble all 4 output segments -------------
__global__ __launch_bounds__(256) void assembly_kernel(
    const float* __restrict__ input, const float* __restrict__ ws_num,
    const float* __restrict__ ws_den, const float* __restrict__ ws_l,
    float* __restrict__ out)
{
    size_t tid = (size_t)blockIdx.x * 256 + threadIdx.x;
    size_t row = tid >> 6;
    int d = (int)(tid & 63) * 4;
    int b = (int)(row >> 11);
    float inv  = 1.0f / (ws_l[row] + ws_l[NB * NL + row]);
    float dinv = 1.0f / ws_den[b];
    float* po = out + row * OUTW;
    float4 in = *(const float4*)(input + row * ND + d);
    float4 pa = *(const float4*)(po + ND + d);
    float4 pb = *(const float4*)(po + 2 * ND + d);
    float4 nu = *(const float4*)(ws_num + b * ND + d);
    float4 o1;
    o1.x = (pa.x + pb.x) * inv; o1.y = (pa.y + pb.y) * inv;
    o1.z = (pa.z + pb.z) * inv; o1.w = (pa.w + pb.w) * inv;
    float4 o2v;
    o2v.x = nu.x * dinv; o2v.y = nu.y * dinv;
    o2v.z = nu.z * dinv; o2v.w = nu.w * dinv;
    *(float4*)(po + d) = in;
    *(float4*)(po + ND + d) = o1;
    float4 q;
    q.x = in.x * o1.x; q.y = in.y * o1.y; q.z = in.z * o1.z; q.w = in.w * o1.w;
    *(float4*)(po + 2 * ND + d) = q;
    float4 r;
    r.x = o2v.x * o1.x; r.y = o2v.y * o1.y; r.z = o2v.z * o1.z; r.w = o2v.w * o1.w;
    *(float4*)(po + 3 * ND + d) = r;
}

// ---- launcher ---------------------------------------------------------------
extern "C" void kernel_launch(void* const* d_in, const int* in_sizes, int n_in,
                              void* d_out, int out_size, void* d_ws, size_t ws_size,
                              hipStream_t stream) {
    const float* input     = (const float*)d_in[0];
    const float* memory    = (const float*)d_in[1];
    const float* mask      = (const float*)d_in[2];
    const float* w_input   = (const float*)d_in[3];
    const float* w_memory  = (const float*)d_in[4];
    const float* dot_scale = (const float*)d_in[5];
    float* out = (float*)d_out;
    char* outc = (char*)d_out;
    float* ws  = (float*)d_ws;

    // ws floats: idot 16K | mbias 16K | l 2x16K | m 2x16K | num 2K | den 8
    float* ws_idot  = ws;
    float* ws_mbias = ws + 16384;
    float* ws_l     = ws + 32768;
    float* ws_m     = ws + 65536;
    float* ws_num   = ws + 98304;
    float* ws_den   = ws + 100352;

    dots_kernel<<<8192, 256, 0, stream>>>(input, memory, mask, w_input,
                                          w_memory, ws_idot, ws_mbias, outc);
    flash_kernel<<<256, 256, FLASH_LDS, stream>>>(input, dot_scale, ws_mbias,
                                                  outc, out, ws_l, ws_m);
    hipMemsetAsync(ws_num, 0, (NB * ND + NB) * sizeof(float), stream);
    o2_kernel<<<128, 256, 0, stream>>>(input, ws_idot, ws_m, ws_num, ws_den);
    assembly_kernel<<<4096, 256, 0, stream>>>(input, ws_num, ws_den, ws_l, out);
}

// Round 6
// 204.229 us; speedup vs baseline: 1.6669x; 1.6669x over previous
//
#include <hip/hip_runtime.h>
#include <hip/hip_bf16.h>

// BiAttention, round 6 = round 5 with the prep_kernel row-major omap fix:
// omap(row*512) already yields +512 for odd rows; the hoisted extra
// (rloc&1)*512 double-counted it and pushed odd K rows out of their chunk
// (read back as zeros -> absmax 0.91). Store now uses per-lane omap (as R4).
//
// Flash core: S^T = K.Q^T, O^T = V^T.P^T, fragment-major LDS (conflict-free
// lane*16 reads), global_load_lds DMA double-buffer, oaccT statically
// indexed everywhere (R4's scratch-demotion fix).

typedef __bf16 bf16_t;
typedef bf16_t bf16x4 __attribute__((ext_vector_type(4)));
typedef bf16_t bf16x8 __attribute__((ext_vector_type(8)));
typedef float  f32x16 __attribute__((ext_vector_type(16)));

#define NB 8
#define NL 2048
#define NM 2048
#define ND 256
#define OUTW 1024
#define MT 32
#define MH 1024
#define NIT 32              // MH/MT
#define LT 128
#define MEMT_X0 8388608u    // byte offset of transposed bf16 copy in seg0 space
#define FLASH_LDS 73728     // 2*32KB kv dbuf + 8KB pfrag

// seg0 byte-space map: flat byte x -> out byte offset. 1KB chunks of x map to
// 4KB-strided rows of out. Any offset added AFTER omap must not cross a 1KB
// chunk in x-space; chunk steps must be added as multiples of 4096.
__device__ __forceinline__ unsigned omap(unsigned x) {
    return ((x >> 10) << 12) | (x & 1023u);
}

__device__ __forceinline__ void dma16(const void* g, void* l) {
    __builtin_amdgcn_global_load_lds(
        (const __attribute__((address_space(1))) unsigned int*)g,
        (__attribute__((address_space(3))) unsigned int*)l, 16, 0, 0);
}

// ---- Kernel A1: idot over input rows ---------------------------------------
__global__ __launch_bounds__(256) void idot_kernel(
    const float* __restrict__ input, const float* __restrict__ w_input,
    float* __restrict__ ws_idot)
{
    int row  = blockIdx.x * 4 + (threadIdx.x >> 6);   // 0..16383
    int lane = threadIdx.x & 63;
    float4 v  = *(const float4*)(input + (size_t)row * ND + lane * 4);
    float4 wv = *(const float4*)(w_input + lane * 4);
    float s = v.x * wv.x + v.y * wv.y + v.z * wv.z + v.w * wv.w;
    #pragma unroll
    for (int off = 1; off < 64; off <<= 1) s += __shfl_xor(s, off, 64);
    if (lane == 0) ws_idot[row] = s;
}

// ---- Kernel A2: mbias + bf16 copies (row-major & transposed) of memory -----
// grid: 8 b * 64 chunks-of-32m = 512 blocks; 256 thr = 4 waves.
__global__ __launch_bounds__(256) void prep_kernel(
    const float* __restrict__ memory, const float* __restrict__ mask,
    const float* __restrict__ w_memory,
    float* __restrict__ ws_mbias, char* __restrict__ outc)
{
    __shared__ __align__(16) bf16_t lds[32 * 256];    // rows m, cols d

    int b  = blockIdx.x >> 6;
    int mc = blockIdx.x & 63;            // 32-m chunk
    int t  = threadIdx.x, w = t >> 6, lane = t & 63;

    float4 wv = *(const float4*)(w_memory + lane * 4);

    #pragma unroll
    for (int it = 0; it < 8; ++it) {
        int rloc = it * 4 + w;                       // 0..31
        int row  = b * NM + mc * 32 + rloc;          // global memory row
        float4 v = *(const float4*)(memory + (size_t)row * ND + lane * 4);
        float s = v.x * wv.x + v.y * wv.y + v.z * wv.z + v.w * wv.w;
        #pragma unroll
        for (int off = 1; off < 64; off <<= 1) s += __shfl_xor(s, off, 64);
        if (lane == 0) ws_mbias[row] = s - 1e30f * (1.0f - mask[row]);
        bf16x4 bv;
        bv[0] = (bf16_t)v.x; bv[1] = (bf16_t)v.y;
        bv[2] = (bf16_t)v.z; bv[3] = (bf16_t)v.w;
        // row-major bf16 copy: per-lane omap (8B granule stays in-chunk)
        unsigned x = 2u * ((unsigned)row * ND + lane * 4);
        *(bf16x4*)(outc + omap(x)) = bv;
        // stage into LDS for transpose
        *(bf16x4*)(&lds[rloc * 256 + lane * 4]) = bv;
    }
    __syncthreads();
    // transposed emit: layout [b][m>>3][d][m&7]; thread t = d column.
    int d = t;
    #pragma unroll
    for (int mc4 = 0; mc4 < 4; ++mc4) {
        bf16x8 pk;
        #pragma unroll
        for (int j = 0; j < 8; ++j) pk[j] = lds[(mc4 * 8 + j) * 256 + d];
        unsigned x = MEMT_X0 +
            2u * ((((unsigned)(b * 256 + mc * 4 + mc4)) * ND + d) * 8);
        *(bf16x8*)(outc + omap(x)) = pk;   // 16B granule, in-chunk ✓
    }
}

// ---- Kernel B: flash attention partials ------------------------------------
// grid 256 = lt*16 + b*2 + half; 4 waves; wave w owns L rows [w*32, w*32+32).
__global__ __launch_bounds__(256, 1) void flash_kernel(
    const float* __restrict__ input, const float* __restrict__ dot_scale,
    const float* __restrict__ ws_mbias, const char* __restrict__ outc,
    float* __restrict__ out, float* __restrict__ ws_l, float* __restrict__ ws_m)
{
    extern __shared__ __align__(16) char smem[];
    // [0,32768): buf0 = kbuf(16K)+vbuf(16K); [32768,65536): buf1; [65536,73728): pfrag

    int bid = blockIdx.x;
    int half = bid & 1, b = (bid >> 1) & 7, lt = bid >> 4;
    int l0 = lt * LT;
    int m_base = half * MH;
    int t = threadIdx.x, w = t >> 6, lane = t & 63;
    int c = lane & 31, h = lane >> 5;

    // Q fragments in registers (B-operand; col = lane&31 = l, k contiguous d)
    const float* qrow = input + (size_t)(b * NL + l0 + w * 32 + c) * ND;
    bf16x8 qf[16];
    #pragma unroll
    for (int ks = 0; ks < 16; ++ks) {
        int d0 = ks * 16 + h * 8;
        float4 a0 = *(const float4*)(qrow + d0);
        float4 a1 = *(const float4*)(qrow + d0 + 4);
        float4 s0 = *(const float4*)(dot_scale + d0);
        float4 s1 = *(const float4*)(dot_scale + d0 + 4);
        qf[ks][0] = (bf16_t)(a0.x * s0.x); qf[ks][1] = (bf16_t)(a0.y * s0.y);
        qf[ks][2] = (bf16_t)(a0.z * s0.z); qf[ks][3] = (bf16_t)(a0.w * s0.w);
        qf[ks][4] = (bf16_t)(a1.x * s1.x); qf[ks][5] = (bf16_t)(a1.y * s1.y);
        qf[ks][6] = (bf16_t)(a1.z * s1.z); qf[ks][7] = (bf16_t)(a1.w * s1.w);
    }

    // Per-lane DMA source bases (mapped through omap once; later increments
    // stay within-chunk or step whole chunks by multiples of 4096).
    unsigned xk = 2u * (((unsigned)(b * NM + m_base + c)) * ND + h * 8);
    const char* kg = outc + omap(xk);
    unsigned xv = MEMT_X0 +
        2u * ((((unsigned)(b * 256 + (m_base >> 3) + h)) * ND + c) * 8);
    const char* vg = outc + omap(xv);

    char* buf0 = smem;
    char* buf1 = smem + 32768;

    // prologue: stage tile 0 into buf0
    #pragma unroll
    for (int j = 0; j < 4; ++j) {
        int i = 4 * w + j;
        int ks = i >> 3, dt = i & 7;
        dma16(kg + i * 32, buf0 + i * 1024);
        dma16(vg + ks * 32768 + (dt >> 1) * 4096 + (dt & 1) * 512,
              buf0 + 16384 + i * 1024);
    }
    kg += 65536; vg += 65536;

    f32x16 oaccT[8];
    #pragma unroll
    for (int i = 0; i < 8; ++i)
        #pragma unroll
        for (int r = 0; r < 16; ++r) oaccT[i][r] = 0.f;
    float lsum = 0.f, mmax = -3e38f;

    const float* mb_base = ws_mbias + b * NM;
    bf16_t* pfw = (bf16_t*)(smem + 65536 + w * 2048);

    #pragma unroll 1
    for (int it = 0; it < NIT; ++it) {
        int m0 = m_base + it * MT;
        asm volatile("s_waitcnt vmcnt(0)" ::: "memory"); // my DMA for cur done
        __syncthreads();                                  // all waves' DMA visible
        const char* cb = (it & 1) ? buf1 : buf0;
        char* nb = (it & 1) ? buf0 : buf1;
        const bf16_t* kb = (const bf16_t*)cb;
        const bf16_t* vb = (const bf16_t*)(cb + 16384);
        if (it + 1 < NIT) {   // stage next tile (safe: barrier above)
            #pragma unroll
            for (int j = 0; j < 4; ++j) {
                int i = 4 * w + j;
                int ks = i >> 3, dt = i & 7;
                dma16(kg + i * 32, nb + i * 1024);
                dma16(vg + ks * 32768 + (dt >> 1) * 4096 + (dt & 1) * 512,
                      nb + 16384 + i * 1024);
            }
            kg += 65536; vg += 65536;
        }
        float mb[16];
        #pragma unroll
        for (int r = 0; r < 16; ++r)
            mb[r] = mb_base[m0 + ((r & 3) + 8 * (r >> 2) + 4 * h)];
        // QK: S^T = K . Q^T (two interleaved accumulator chains)
        f32x16 Sa, Sb;
        #pragma unroll
        for (int r = 0; r < 16; ++r) { Sa[r] = 0.f; Sb[r] = 0.f; }
        #pragma unroll
        for (int ks = 0; ks < 16; ks += 2) {
            bf16x8 k0 = *(const bf16x8*)(kb + ks * 512 + lane * 8);
            bf16x8 k1 = *(const bf16x8*)(kb + (ks + 1) * 512 + lane * 8);
            Sa = __builtin_amdgcn_mfma_f32_32x32x16_bf16(k0, qf[ks], Sa, 0, 0, 0);
            Sb = __builtin_amdgcn_mfma_f32_32x32x16_bf16(k1, qf[ks + 1], Sb, 0, 0, 0);
        }
        // P^T = exp(S^T + mdot): pack 4 consecutive m per lane -> b64 writes
        #pragma unroll
        for (int j2 = 0; j2 < 4; ++j2) {
            bf16x4 pk;
            #pragma unroll
            for (int q = 0; q < 4; ++q) {
                int r = j2 * 4 + q;
                float v = Sa[r] + Sb[r] + mb[r];
                mmax = fmaxf(mmax, v);
                float e = __expf(v);
                lsum += e;
                pk[q] = (bf16_t)e;
            }
            *(bf16x4*)(pfw + j2 * 256 + c * 8 + h * 4) = pk;
        }
        asm volatile("s_waitcnt lgkmcnt(0)" ::: "memory");
        // PV: O^T += V^T . P^T (8 independent d-tiles per ks)
        #pragma unroll
        for (int ks = 0; ks < 2; ++ks) {
            bf16x8 pb = *(const bf16x8*)(pfw + ks * 512 + lane * 8);
            #pragma unroll
            for (int dt = 0; dt < 8; ++dt) {
                bf16x8 vv = *(const bf16x8*)(vb + (ks * 8 + dt) * 512 + lane * 8);
                oaccT[dt] = __builtin_amdgcn_mfma_f32_32x32x16_bf16(vv, pb, oaccT[dt], 0, 0, 0);
            }
        }
    }

    // l-sum / row-max finalize (per-lane over m, + h-half merge)
    mmax = fmaxf(mmax, __shfl_xor(mmax, 32, 64));
    lsum += __shfl_xor(lsum, 32, 64);
    if (lane < 32) {
        int row = b * NL + l0 + w * 32 + lane;
        ws_l[half * (NB * NL) + row] = lsum;
        ws_m[half * (NB * NL) + row] = mmax;
    }
    // epilogue: O^T -> coalesced O via per-wave LDS patch (in dead buf0 space;
    // last iter (it=31, odd) read buf1). FULLY UNROLLED: oaccT must only ever
    // be indexed by compile-time constants or it is demoted to scratch.
    float* patch = (float*)(smem + w * 4352);   // [32 d][stride 33] floats
    float* oseg = out + (size_t)(b * NL + l0 + w * 32) * OUTW + ND * (1 + half);
    #pragma unroll
    for (int dt = 0; dt < 8; ++dt) {
        asm volatile("s_waitcnt lgkmcnt(0)" ::: "memory");
        #pragma unroll
        for (int r = 0; r < 16; ++r)
            patch[((r & 3) + 8 * (r >> 2) + 4 * h) * 33 + c] = oaccT[dt][r];
        asm volatile("s_waitcnt lgkmcnt(0)" ::: "memory");
        #pragma unroll
        for (int rr = 0; rr < 16; ++rr) {
            float val = patch[c * 33 + rr * 2 + h];
            oseg[(size_t)(rr * 2 + h) * OUTW + dt * 32 + c] = val;
        }
    }
}

// ---- Kernel C: output_two numerator/denominator (no separate softmax) ------
__global__ __launch_bounds__(256) void o2_kernel(
    const float* __restrict__ input, const float* __restrict__ ws_idot,
    const float* __restrict__ ws_m, float* __restrict__ ws_num,
    float* __restrict__ ws_den)
{
    int b = blockIdx.x >> 4, slice = blockIdx.x & 15;
    int t = threadIdx.x;
    int lgrp = t >> 6, d4 = (t & 63) * 4;
    float4 acc = {0.f, 0.f, 0.f, 0.f};
    float esum = 0.f;
    for (int i = 0; i < 32; ++i) {
        int row = b * NL + slice * 128 + lgrp * 32 + i;
        float e = __expf(ws_idot[row] + fmaxf(ws_m[row], ws_m[NB * NL + row]));
        float4 v = *(const float4*)(input + (size_t)row * ND + d4);
        acc.x += e * v.x; acc.y += e * v.y;
        acc.z += e * v.z; acc.w += e * v.w;
        esum += e;
    }
    float* dst = ws_num + b * ND + d4;
    atomicAdd(dst + 0, acc.x); atomicAdd(dst + 1, acc.y);
    atomicAdd(dst + 2, acc.z); atomicAdd(dst + 3, acc.w);
    if ((t & 63) == 0) atomicAdd(ws_den + b, esum);
}

// ---- Kernel D: combine halves + assemble all 4 output segments -------------
__global__ __launch_bounds__(256) void assembly_kernel(
    const float* __restrict__ input, const float* __restrict__ ws_num,
    const float* __restrict__ ws_den, const float* __restrict__ ws_l,
    float* __restrict__ out)
{
    size_t tid = (size_t)blockIdx.x * 256 + threadIdx.x;
    size_t row = tid >> 6;
    int d = (int)(tid & 63) * 4;
    int b = (int)(row >> 11);
    float inv  = 1.0f / (ws_l[row] + ws_l[NB * NL + row]);
    float dinv = 1.0f / ws_den[b];
    float* po = out + row * OUTW;
    float4 in = *(const float4*)(input + row * ND + d);
    float4 pa = *(const float4*)(po + ND + d);
    float4 pb = *(const float4*)(po + 2 * ND + d);
    float4 nu = *(const float4*)(ws_num + b * ND + d);
    float4 o1;
    o1.x = (pa.x + pb.x) * inv; o1.y = (pa.y + pb.y) * inv;
    o1.z = (pa.z + pb.z) * inv; o1.w = (pa.w + pb.w) * inv;
    float4 o2v;
    o2v.x = nu.x * dinv; o2v.y = nu.y * dinv;
    o2v.z = nu.z * dinv; o2v.w = nu.w * dinv;
    *(float4*)(po + d) = in;
    *(float4*)(po + ND + d) = o1;
    float4 q;
    q.x = in.x * o1.x; q.y = in.y * o1.y; q.z = in.z * o1.z; q.w = in.w * o1.w;
    *(float4*)(po + 2 * ND + d) = q;
    float4 r;
    r.x = o2v.x * o1.x; r.y = o2v.y * o1.y; r.z = o2v.z * o1.z; r.w = o2v.w * o1.w;
    *(float4*)(po + 3 * ND + d) = r;
}

// ---- launcher ---------------------------------------------------------------
extern "C" void kernel_launch(void* const* d_in, const int* in_sizes, int n_in,
                              void* d_out, int out_size, void* d_ws, size_t ws_size,
                              hipStream_t stream) {
    const float* input     = (const float*)d_in[0];
    const float* memory    = (const float*)d_in[1];
    const float* mask      = (const float*)d_in[2];
    const float* w_input   = (const float*)d_in[3];
    const float* w_memory  = (const float*)d_in[4];
    const float* dot_scale = (const float*)d_in[5];
    float* out = (float*)d_out;
    char* outc = (char*)d_out;
    float* ws  = (float*)d_ws;

    // ws floats: idot 16K | mbias 16K | l 2x16K | m 2x16K | num 2K | den 8
    float* ws_idot  = ws;
    float* ws_mbias = ws + 16384;
    float* ws_l     = ws + 32768;
    float* ws_m     = ws + 65536;
    float* ws_num   = ws + 98304;
    float* ws_den   = ws + 100352;

    idot_kernel<<<4096, 256, 0, stream>>>(input, w_input, ws_idot);
    prep_kernel<<<512, 256, 0, stream>>>(memory, mask, w_memory, ws_mbias, outc);
    flash_kernel<<<256, 256, FLASH_LDS, stream>>>(input, dot_scale, ws_mbias,
                                                  outc, out, ws_l, ws_m);
    hipMemsetAsync(ws_num, 0, (NB * ND + NB) * sizeof(float), stream);
    o2_kernel<<<128, 256, 0, stream>>>(input, ws_idot, ws_m, ws_num, ws_den);
    assembly_kernel<<<4096, 256, 0, stream>>>(input, ws_num, ws_den, ws_l, out);
}